// Round 13
// baseline (245.015 us; speedup 1.0000x reference)
//
#include <hip/hip_runtime.h>

// ---------------------------------------------------------------------------
// GGNN message passing, MI355X/gfx950.  Round 22 = R21 + hidden-tier MLP/TLP.
//   R21 post-mortem: single-pass CSR +6.2us (best 234.9).  Hidden tier still
//   ~172us over memset+prep_fill+gather, each kernel <=62.2 (top-5 cap) but
//   bottom-up floors are ~25+20us -> both run 2-3x above floor; signature =
//   MLP=1 chains (fill: one edge/thread) and serial per-wave segments
//   (gather: 4 segs/wave).  This round, layout-preserving:
//     - gather: 2 waves/node (2 segs each, 100K waves), int4 csrF reads;
//       cnt4f written as two float2 halves (same bytes).
//     - prep_fill: 32B/thread convert, 2 edges/thread fill (MLP=2).
//     - weight-pack moved into the gather launch (only agg_gru needs it;
//       overlaps gather's latency phase, shortens prep->gather path).
//   agg_gru verbatim R19/R20/R21 (62.5us control).
// Lessons: no gather-into-GEMM fusion (R6); no K-merging (R7); LDS-staged
// coalesced out stores (R5); watch WRITE_SIZE for spill (R12); weights must
// be LDS-staged (R16); NO cooperative kernels / grid.sync ~100us (R14/R17);
// wave-per-node gather beats wave-per-segment (R15); agg_gru retunes null
// at ~65us (R18/R19); launch overhead negligible under graph replay (R20).
// ---------------------------------------------------------------------------

typedef __attribute__((ext_vector_type(8))) short short8;
typedef __attribute__((ext_vector_type(4))) float floatx4;

#define HID 128
#define NTY 4
#define CAP 16
#define OVF_MAX 65536

__device__ __forceinline__ unsigned short f2bf(float f) {
    unsigned int u = __float_as_uint(f);
    unsigned int r = (u + 0x7fffu + ((u >> 16) & 1u)) >> 16;  // RNE
    return (unsigned short)r;
}
__device__ __forceinline__ float bf2f(unsigned int lo16) {
    return __uint_as_float(lo16 << 16);
}
__device__ __forceinline__ float frcp(float x) { return __builtin_amdgcn_rcpf(x); }

// 16B global->LDS DMA: per-lane global src, wave-uniform LDS base + lane*16.
__device__ __forceinline__ void gload16(const unsigned short* g, unsigned short* l) {
    __builtin_amdgcn_global_load_lds(
        (const __attribute__((address_space(1))) unsigned int*)g,
        (__attribute__((address_space(3))) unsigned int*)l,
        16, 0, 0);
}

// ---- prep_fill v2: cvt_h (32B/thread) | bucket-fill (2 edges/thread) ------
// cnti + ovfn pre-zeroed by hipMemsetAsync.  Weight packing moved out.

__global__ void prep_fill_kernel(const float* __restrict__ h, unsigned short* __restrict__ hbf,
                                 const int* __restrict__ src, const int* __restrict__ dst,
                                 const int* __restrict__ ety,
                                 int* __restrict__ cnti, int* __restrict__ csrF,
                                 int* __restrict__ ovfn, int2* __restrict__ ovf,
                                 int total4, int nb_cvt, int E) {
    int b = blockIdx.x, tt = threadIdx.x;
    if (b < nb_cvt) {
        int i0 = (b * 256 + tt) * 2;
#pragma unroll
        for (int k = 0; k < 2; ++k) {
            int i = i0 + k;
            if (i < total4) {
                float4 v = ((const float4*)h)[i];
                uint2 o;
                o.x = (unsigned int)f2bf(v.x) | ((unsigned int)f2bf(v.y) << 16);
                o.y = (unsigned int)f2bf(v.z) | ((unsigned int)f2bf(v.w) << 16);
                ((uint2*)hbf)[i] = o;
            }
        }
    } else {
        int base = (b - nb_cvt) * 512;
        int e0 = base + tt;
        int e1 = base + 256 + tt;
        // issue both edge reads up front (MLP=2 on the atomic->store chains)
        int d0 = 0, t0 = 0, s0 = 0, d1 = 0, t1 = 0, s1 = 0;
        bool v0 = e0 < E, v1 = e1 < E;
        if (v0) { d0 = dst[e0]; t0 = ety[e0]; s0 = src[e0]; }
        if (v1) { d1 = dst[e1]; t1 = ety[e1]; s1 = src[e1]; }
        if (v0) {
            int seg = d0 * 4 + t0;
            int pos = atomicAdd(&cnti[seg], 1);
            if (pos < CAP) csrF[(size_t)seg * CAP + pos] = s0;
            else {
                int op = atomicAdd(ovfn, 1);
                if (op < OVF_MAX) ovf[op] = make_int2(seg, s0);
            }
        }
        if (v1) {
            int seg = d1 * 4 + t1;
            int pos = atomicAdd(&cnti[seg], 1);
            if (pos < CAP) csrF[(size_t)seg * CAP + pos] = s1;
            else {
                int op = atomicAdd(ovfn, 1);
                if (op < OVF_MAX) ovf[op] = make_int2(seg, s1);
            }
        }
    }
}

// ---- gather_plus: weight-pack blocks + gather (2 waves/node) --------------
// Blocks [0,769): pack Wc/Wg/bias4 (feeds agg_gru only; overlaps gather).
// Blocks [769,..): 4 waves = 2 nodes; wave handles 2 segments.
// Su[seg*64+lane] layout identical to R21; cnt4f written as float2 halves.

__global__ void gather_plus_kernel(const float* __restrict__ W, unsigned short* __restrict__ Wc,
                                   const float* __restrict__ w_ih, const float* __restrict__ w_hh,
                                   unsigned short* __restrict__ Wg, float* __restrict__ bias4,
                                   const float* __restrict__ b_ih, const float* __restrict__ b_hh,
                                   const int* __restrict__ cnti, const int* __restrict__ csrF,
                                   const unsigned int* __restrict__ hbu,
                                   const int* __restrict__ ovfn, const int2* __restrict__ ovf,
                                   float* __restrict__ cnt2f, unsigned int* __restrict__ Su, int N) {
    int b = blockIdx.x, tt = threadIdx.x;
    if (b < 256) {
        // Wcat[j][t*128+k] = edge_W[t][j][k]  (128 x 512)
        int idx = b * 256 + tt;
        int j = idx >> 9, rem = idx & 511;
        int t = rem >> 7, k = rem & 127;
        Wc[idx] = f2bf(W[(t * HID + j) * HID + k]);
        return;
    } else if (b < 768) {
        // Wg[512][256]: rows 4j+{0,1,2,3} = r|z|i_n|h_n; cols 0-127 agg, 128-255 h
        int idx = (b - 256) * 256 + tt;
        int row = idx >> 8, k = idx & 255;
        int j = row >> 2, g = row & 3;
        float v = 0.0f;
        if (g == 0) v = (k < 128) ? w_ih[j * 128 + k]         : w_hh[j * 128 + (k - 128)];
        else if (g == 1) v = (k < 128) ? w_ih[(128 + j) * 128 + k] : w_hh[(128 + j) * 128 + (k - 128)];
        else if (g == 2) v = (k < 128) ? w_ih[(256 + j) * 128 + k] : 0.0f;
        else             v = (k < 128) ? 0.0f : w_hh[(256 + j) * 128 + (k - 128)];
        Wg[idx] = f2bf(v);
        return;
    } else if (b == 768) {
        if (tt < 128) {
            float4 v;
            v.x = b_ih[tt] + b_hh[tt];
            v.y = b_ih[128 + tt] + b_hh[128 + tt];
            v.z = b_ih[256 + tt];
            v.w = b_hh[256 + tt];
            ((float4*)bias4)[tt] = v;
        }
        return;
    }

    // gather: block covers 2 nodes; wave wv: node = gb*2 + (wv>>1), half = wv&1
    int gb = b - 769;
    int wv = tt >> 6;
    int lane = tt & 63;
    int node = gb * 2 + (wv >> 1);
    if (node >= N) return;
    int half = wv & 1;
    int seg0 = node * 4 + half * 2;

    int tot[2];
    tot[0] = __builtin_amdgcn_readfirstlane(cnti[seg0]);
    tot[1] = __builtin_amdgcn_readfirstlane(cnti[seg0 + 1]);

#pragma unroll
    for (int t = 0; t < 2; ++t) {
        int seg = seg0 + t;
        int c = (tot[t] < CAP) ? tot[t] : CAP;
        int4 pq[4];
#pragma unroll
        for (int q = 0; q < 4; ++q)
            if (q * 4 < c) pq[q] = ((const int4*)csrF)[(size_t)seg * 4 + q];
        int p[CAP];
#pragma unroll
        for (int q = 0; q < 4; ++q) {
            p[q * 4 + 0] = pq[q].x; p[q * 4 + 1] = pq[q].y;
            p[q * 4 + 2] = pq[q].z; p[q * 4 + 3] = pq[q].w;
        }
        unsigned int u[CAP];
#pragma unroll
        for (int i = 0; i < CAP; ++i) if (i < c) u[i] = hbu[(size_t)p[i] * 64 + lane];
        float s0 = 0.f, s1 = 0.f;
#pragma unroll
        for (int i = 0; i < CAP; ++i) {
            if (i < c) {
                s0 += bf2f(u[i] & 0xffffu);
                s1 += bf2f(u[i] >> 16);
            }
        }
        if (tot[t] > CAP) {   // rare: walk overflow list (correctness path)
            int on = __builtin_amdgcn_readfirstlane(ovfn[0]);
            if (on > OVF_MAX) on = OVF_MAX;
            for (int k = 0; k < on; ++k) {
                int2 oe = ovf[k];
                if (oe.x == seg) {
                    unsigned int uu = hbu[(size_t)oe.y * 64 + lane];
                    s0 += bf2f(uu & 0xffffu);
                    s1 += bf2f(uu >> 16);
                }
            }
        }
        Su[(size_t)seg * 64 + lane] = (unsigned int)f2bf(s0) | ((unsigned int)f2bf(s1) << 16);
    }
    if (lane == 0) {
        // cnt4f[node] halves: float2 at (node*2 + half)
        ((float2*)cnt2f)[(size_t)node * 2 + half] = make_float2((float)tot[0], (float)tot[1]);
    }
}

// ---- agg_gru v8 (verbatim R19-R21, 62.5us control): DMA-staged GEMM->GRU --
// 32-node tile, 256 threads (4 waves), 48KB LDS:
//   Sreg/Xagg overlay @0 (8KB) | Hbt @8192 (8KB) | Wreg @16384 (32KB);
//   OutsF (16KB) overlays Wreg in the epilogue.
// Staging = gload16 DMA: LDS linear, global source INVERSE-swizzled
// (LDS[row][x] = global[row][x^(row&7)]); reads XOR (both-sides pattern).

__global__ __launch_bounds__(256, 3) void agg_gru(const unsigned short* __restrict__ S,
                                                  const unsigned short* __restrict__ Wc,
                                                  const unsigned short* __restrict__ Wg,
                                                  const unsigned short* __restrict__ hbf,
                                                  const float4* __restrict__ cnt4,
                                                  const float* __restrict__ eb,
                                                  const float4* __restrict__ bias4,
                                                  float* __restrict__ out, int M) {
    __shared__ __align__(16) unsigned char smem[49152];
    unsigned short* Sreg = (unsigned short*)smem;            // 8KB; Xagg overlay
    unsigned short* Hbt  = (unsigned short*)(smem + 8192);   // 8KB
    unsigned short* Wreg = (unsigned short*)(smem + 16384);  // 32KB
    unsigned short* Xag  = Sreg;                             // overlay after phase A
    float* OutsF = (float*)(smem + 16384);                   // epilogue overlay

    const int tid = threadIdx.x;
    const int m0 = blockIdx.x * 32;
    const int lane = tid & 63, w = tid >> 6;   // w in 0..3
    const int lm = lane & 15, quad = lane >> 4;

    // ---- phase A: agg = S @ Wc^T, K=512, BK=128 ----
    floatx4 accA[2][2];
#pragma unroll
    for (int x = 0; x < 2; ++x)
#pragma unroll
        for (int y = 0; y < 2; ++y) accA[x][y] = (floatx4){0.f, 0.f, 0.f, 0.f};

#pragma unroll 1
    for (int c = 0; c < 4; ++c) {
        // DMA S c-slice -> Sreg (8KB = 8 chunks; wave w does 2)
#pragma unroll
        for (int i = 0; i < 2; ++i) {
            int k = w * 2 + i;
            int slot = k * 64 + lane;
            int row = slot >> 4, x = slot & 15;
            int grow = m0 + row; if (grow >= M) grow = M - 1;
            gload16(S + (size_t)grow * 512 + c * 128 + ((x ^ (row & 7)) << 3),
                    Sreg + k * 512);
        }
        // DMA Wc c-slice -> Wreg (32KB = 32 chunks; wave w does 8)
#pragma unroll
        for (int i = 0; i < 8; ++i) {
            int kk = w * 8 + i;
            int slot = kk * 64 + lane;
            int j = slot >> 4, x = slot & 15;
            gload16(Wc + (size_t)j * 512 + c * 128 + ((x ^ (j & 7)) << 3),
                    Wreg + kk * 512);
        }
        __syncthreads();   // drains DMA (vmcnt) + orders for all waves
#pragma unroll
        for (int ss = 0; ss < 4; ++ss) {
            int g = ss * 4 + quad;
            short8 av[2], bw[2];
#pragma unroll
            for (int mi = 0; mi < 2; ++mi)
                av[mi] = *(const short8*)&Sreg[(mi * 16 + lm) * 128 + ((g ^ (lm & 7)) << 3)];
#pragma unroll
            for (int ni = 0; ni < 2; ++ni)
                bw[ni] = *(const short8*)&Wreg[(w * 32 + ni * 16 + lm) * 128 + ((g ^ (lm & 7)) << 3)];
#pragma unroll
            for (int mi = 0; mi < 2; ++mi)
#pragma unroll
                for (int ni = 0; ni < 2; ++ni)
                    accA[mi][ni] = __builtin_amdgcn_mfma_f32_16x16x32_bf16(av[mi], bw[ni], accA[mi][ni], 0, 0, 0);
        }
        __syncthreads();   // WAR: next c overwrites Sreg/Wreg; last iter frees Sreg
    }

    // DMA Hbt (h tile, 8KB = 8 chunks; wave w does 2) -- independent region
#pragma unroll
    for (int i = 0; i < 2; ++i) {
        int k = w * 2 + i;
        int slot = k * 64 + lane;
        int row = slot >> 4, x = slot & 15;
        int grow = m0 + row; if (grow >= M) grow = M - 1;
        gload16(hbf + (size_t)grow * HID + ((x ^ (row & 7)) << 3),
                Hbt + k * 512);
    }

    // handoff: agg(+cnt.eb) -> Xagg (Sreg region; phase-A reads fenced)
    {
#pragma unroll
        for (int ni = 0; ni < 2; ++ni) {
            int j = w * 32 + ni * 16 + lm;
            float e0 = eb[j], e1 = eb[HID + j], e2 = eb[2 * HID + j], e3 = eb[3 * HID + j];
            int jg = j >> 3, jr = j & 7;
#pragma unroll
            for (int mi = 0; mi < 2; ++mi) {
#pragma unroll
                for (int r = 0; r < 4; ++r) {
                    int nl = mi * 16 + quad * 4 + r;          // 0..31
                    int gn = m0 + nl;
                    if (gn >= M) gn = M - 1;
                    float4 c4 = cnt4[gn];
                    float v = accA[mi][ni][r] + c4.x * e0 + c4.y * e1 + c4.z * e2 + c4.w * e3;
                    Xag[nl * 128 + ((jg ^ (nl & 7)) << 3) + jr] = f2bf(v);
                }
            }
        }
    }
    __syncthreads();  // Xagg + Hbt DMA visible to all waves

    // ---- phase B: 4 gate chunks x 2 kc halves ----
    float fin[4][2][2];

#pragma unroll 1
    for (int gc = 0; gc < 4; ++gc) {
        floatx4 acc2[2][2];
#pragma unroll
        for (int x = 0; x < 2; ++x)
#pragma unroll
            for (int y = 0; y < 2; ++y) acc2[x][y] = (floatx4){0.f, 0.f, 0.f, 0.f};

#pragma unroll 1
        for (int kc = 0; kc < 2; ++kc) {
            // DMA Wg chunk slice (32KB = 32 chunks; wave w does 8)
#pragma unroll
            for (int i = 0; i < 8; ++i) {
                int kk = w * 8 + i;
                int slot = kk * 64 + lane;
                int rr = slot >> 4, x = slot & 15;
                gload16(Wg + (size_t)(gc * 128 + rr) * 256 + kc * 128 + ((x ^ (rr & 7)) << 3),
                        Wreg + kk * 512);
            }
            __syncthreads();
            const unsigned short* Bsrc = kc ? Hbt : Xag;
#pragma unroll
            for (int ss = 0; ss < 4; ++ss) {
                int g = ss * 4 + quad;
                short8 af[2], bfr[2];
#pragma unroll
                for (int mi2 = 0; mi2 < 2; ++mi2)
                    af[mi2] = *(const short8*)&Wreg[(w * 32 + mi2 * 16 + lm) * 128 + ((g ^ (lm & 7)) << 3)];
#pragma unroll
                for (int ni = 0; ni < 2; ++ni)
                    bfr[ni] = *(const short8*)&Bsrc[(ni * 16 + lm) * 128 + ((g ^ (lm & 7)) << 3)];
#pragma unroll
                for (int mi2 = 0; mi2 < 2; ++mi2)
#pragma unroll
                    for (int ni = 0; ni < 2; ++ni)
                        acc2[mi2][ni] = __builtin_amdgcn_mfma_f32_16x16x32_bf16(af[mi2], bfr[ni], acc2[mi2][ni], 0, 0, 0);
            }
            __syncthreads();  // WAR before next Wg stage
        }

        // GRU math: gate row = gc*128 + w*32 + mi2*16 + quad*4 + g
        //   -> j = gc*32 + w*8 + mi2*4 + quad, gate g = reg index
#pragma unroll
        for (int mi2 = 0; mi2 < 2; ++mi2) {
            int j = gc * 32 + w * 8 + mi2 * 4 + quad;   // 0..127
            float4 bb = bias4[j];                       // {b_r,b_z,b_in,b_hn}
            int jg = j >> 3, jr = j & 7;
#pragma unroll
            for (int ni = 0; ni < 2; ++ni) {
                int nl = ni * 16 + lm;
                float g0 = acc2[mi2][ni][0], g1 = acc2[mi2][ni][1];
                float g2 = acc2[mi2][ni][2], g3 = acc2[mi2][ni][3];
                float rr = frcp(1.f + __expf(-(g0 + bb.x)));
                float zz = frcp(1.f + __expf(-(g1 + bb.y)));
                float aa = g2 + bb.z + rr * (g3 + bb.w);
                float nn = 1.f - 2.f * frcp(1.f + __expf(2.f * aa));  // tanh
                float hv = bf2f((unsigned int)Hbt[nl * 128 + ((jg ^ (nl & 7)) << 3) + jr]);
                fin[gc][mi2][ni] = nn + zz * (hv - nn);
            }
        }
    }
    __syncthreads();  // all Wreg/Hbt/Xag reads done -> Outs overlay safe

    // fin -> Outs (f32, swizzled: 4-float group gq at gq^(row&7))
#pragma unroll
    for (int gc = 0; gc < 4; ++gc) {
#pragma unroll
        for (int mi2 = 0; mi2 < 2; ++mi2) {
            int j = gc * 32 + w * 8 + mi2 * 4 + quad;
            int gq = j >> 2, jr = j & 3;
#pragma unroll
            for (int ni = 0; ni < 2; ++ni) {
                int nl = ni * 16 + lm;
                OutsF[nl * 128 + ((gq ^ (nl & 7)) << 2) + jr] = fin[gc][mi2][ni];
            }
        }
    }
    __syncthreads();

    // coalesced store: 32 nodes x 128 floats
    {
        int row = tid >> 3;              // 0..31
        int cb = (tid & 7) * 16;         // 0..112
        int node = m0 + row;
        if (node < M) {
            float* dstp = out + (size_t)node * HID + cb;
#pragma unroll
            for (int i = 0; i < 4; ++i) {
                int gq = (cb >> 2) + i;
                *(float4*)(dstp + i * 4) = *(const float4*)&OutsF[row * 128 + ((gq ^ (row & 7)) << 2)];
            }
        }
    }
}

// ---------------------------------------------------------------------------

extern "C" void kernel_launch(void* const* d_in, const int* in_sizes, int n_in,
                              void* d_out, int out_size, void* d_ws, size_t ws_size,
                              hipStream_t stream) {
    const float* node_states = (const float*)d_in[0];
    const int*   edge_index  = (const int*)d_in[1];
    const int*   edge_type   = (const int*)d_in[2];
    const float* edge_W      = (const float*)d_in[3];
    const float* edge_b      = (const float*)d_in[4];
    const float* w_ih        = (const float*)d_in[5];
    const float* w_hh        = (const float*)d_in[6];
    const float* b_ih        = (const float*)d_in[7];
    const float* b_hh        = (const float*)d_in[8];

    const int M = in_sizes[0] / HID;      // 50000 nodes
    const int E = in_sizes[1] / 2;        // 625000 edges
    const int N4 = M * 4;                 // 200000 (dst,type) segments
    const int* src = edge_index;
    const int* dst = edge_index + E;

    // workspace layout (~79 MB, identical to R21)
    char* ws = (char*)d_ws;
    size_t off = 0;
    unsigned short* hbf   = (unsigned short*)(ws + off); off += (size_t)M * HID * 2;      // 12.8MB
    float*          bias4 = (float*)(ws + off);          off += (size_t)128 * 4 * 4;      // 2KB
    unsigned short* S     = (unsigned short*)(ws + off); off += (size_t)M * 512 * 2;      // 51.2MB
    unsigned short* Wcat  = (unsigned short*)(ws + off); off += (size_t)128 * 512 * 2;    // 128KB
    unsigned short* Wgru  = (unsigned short*)(ws + off); off += (size_t)512 * 256 * 2;    // 256KB
    float*          cnt4f = (float*)(ws + off);          off += (size_t)M * 4 * 4;        // 800KB
    int*            cnti  = (int*)(ws + off);            off += (size_t)N4 * 4;           // 800KB
    int*            ovfn  = (int*)(ws + off);            off += 16;                       // 16B
    int2*           ovf   = (int2*)(ws + off);           off += (size_t)OVF_MAX * 8;      // 512KB
    int*            csrF  = (int*)(ws + off);            off += (size_t)N4 * CAP * 4;     // 12.8MB

    const int total4 = M * HID / 4;
    const int nb_cvt  = (total4 + 511) / 512;    // 3125 (32B/thread)
    const int nb_fill = (E + 511) / 512;         // 1221 (2 edges/thread)

    // zero cnti + ovfn in one SDMA memset (contiguous)
    hipMemsetAsync(cnti, 0, (size_t)N4 * 4 + 16, stream);

    prep_fill_kernel<<<nb_cvt + nb_fill, 256, 0, stream>>>(
        node_states, hbf, src, dst, edge_type, cnti, csrF, ovfn, ovf,
        total4, nb_cvt, E);

    // 769 weight-pack blocks + 25000 gather blocks (2 nodes each)
    gather_plus_kernel<<<769 + (M + 1) / 2, 256, 0, stream>>>(
        edge_W, Wcat, w_ih, w_hh, Wgru, bias4, b_ih, b_hh,
        cnti, csrF, (const unsigned int*)hbf, ovfn, ovf,
        cnt4f, (unsigned int*)S, M);

    agg_gru<<<(M + 31) / 32, 256, 0, stream>>>(S, Wcat, Wgru, hbf, (const float4*)cnt4f,
                                               edge_b, (const float4*)bias4, (float*)d_out, M);
}